// Round 3
// baseline (814.138 us; speedup 1.0000x reference)
//
#include <hip/hip_runtime.h>
#include <stdint.h>
#include <math.h>

#define T_DIM 8192
#define D_DIM 4096
#define E_DIM 64
#define TE (T_DIM * E_DIM)  // 524288
#define GAP_MARGIN 4e-3     // > 2x provable worst-case bf16-split logit error (9.4e-4)
#define ROWS 16             // rows per block
#define NKSTEP (D_DIM / 32) // 128 MFMA k-steps

typedef __attribute__((ext_vector_type(8))) short short8_t;  // 8 bf16 (4 VGPRs)
typedef __attribute__((ext_vector_type(4))) float f32x4;

// ============================================================================
// W bf16 hi/lo planes in fragment-linear order, filled once per call by
// w_split_kernel. idx = ks*2048 + subE*512 + q*128 + ee*8 + j where
// e = subE*16+ee, k = ks*32 + q*8 + j. The per-wave B-fragment read
// (n=lane&15 -> ee, q=lane>>4) is a fully-coalesced 1KB global_load_dwordx4
// per wave at address plane + ks*2048 + b_off — B never touches LDS.
// ============================================================================
__device__ __align__(16) short Whi_g[E_DIM * D_DIM];  // 512 KB
__device__ __align__(16) short Wlo_g[E_DIM * D_DIM];  // 512 KB

// ============================================================================
// Threefry-2x32, key = (0, 42), 20 rounds — VALIDATED (prior session r3/4/5)
// ============================================================================
__device__ __forceinline__ void threefry2x32_k42(uint32_t x0, uint32_t x1,
                                                 uint32_t& o0, uint32_t& o1) {
  const uint32_t ks0 = 0u, ks1 = 42u;
  const uint32_t ks2 = 0x1BD11BDAu ^ ks0 ^ ks1;
  x0 += ks0; x1 += ks1;
#define TF_RND(r) { x0 += x1; x1 = (x1 << (r)) | (x1 >> (32 - (r))); x1 ^= x0; }
  TF_RND(13) TF_RND(15) TF_RND(26) TF_RND(6)   x0 += ks1; x1 += ks2 + 1u;
  TF_RND(17) TF_RND(29) TF_RND(16) TF_RND(24)  x0 += ks2; x1 += ks0 + 2u;
  TF_RND(13) TF_RND(15) TF_RND(26) TF_RND(6)   x0 += ks0; x1 += ks1 + 3u;
  TF_RND(17) TF_RND(29) TF_RND(16) TF_RND(24)  x0 += ks1; x1 += ks2 + 4u;
  TF_RND(13) TF_RND(15) TF_RND(26) TF_RND(6)   x0 += ks2; x1 += ks0 + 5u;
#undef TF_RND
  o0 = x0; o1 = x1;
}

__device__ __forceinline__ uint32_t jax_random_bits32(uint32_t j) {
  uint32_t o0, o1;
  threefry2x32_k42(0u, j, o0, o1);
  return o0 ^ o1;
}

// f64 finalize per row (lane = expert) — VALIDATED, unchanged
__device__ __forceinline__ void finalize_row_f64(double logit, int e, int t,
                                                 float& mask_out, float& weight_out,
                                                 double& gap_out) {
  double m = logit;
#pragma unroll
  for (int off = 1; off < 64; off <<= 1) {
    const double om = __shfl_xor(m, off, 64);
    m = (om > m) ? om : m;
  }
  const double pe = exp(logit - m);
  double s = pe;
#pragma unroll
  for (int off = 1; off < 64; off <<= 1) s += __shfl_xor(s, off, 64);
  weight_out = (float)(pe / s);

  const int idx = t * 64 + e;
  const uint32_t bits = jax_random_bits32((uint32_t)idx);
  const float f01 = __uint_as_float((bits >> 9) | 0x3f800000u) - 1.0f;
  const float minv = 1e-6f;
  const float maxv = 0.999999f;
  float u = __fadd_rn(__fmul_rn(f01, maxv - minv), minv);
  u = fmaxf(minv, u);
  const double g = -log(-log((double)u));
  const double sel = logit + g;

  float mask = 0.0f;
  double cur = sel;
  double v8 = 0.0, v9 = 0.0;
  for (int it = 0; it < 9; ++it) {
    double v = cur;
    int vi = e;
#pragma unroll
    for (int off = 1; off < 64; off <<= 1) {
      const double ov = __shfl_xor(v, off, 64);
      const int    oi = __shfl_xor(vi, off, 64);
      if (ov > v || (ov == v && oi < vi)) { v = ov; vi = oi; }
    }
    if (it < 8) {
      if (vi == e) { mask = 1.0f; cur = -__builtin_inf(); }
      if (it == 7) v8 = v;
    } else {
      v9 = v;
    }
  }
  mask_out = mask;
  gap_out = v8 - v9;
}

// fp32 -> bf16 (RNE, finite inputs only)
__device__ __forceinline__ uint16_t f2bf(float f) {
  const uint32_t x = __float_as_uint(f);
  return (uint16_t)((x + 0x7FFFu + ((x >> 16) & 1u)) >> 16);
}

// split 8 consecutive floats into bf16 hi/lo short8 fragments
__device__ __forceinline__ void split8(const float4 a, const float4 b,
                                       short8_t& hi, short8_t& lo) {
  const float f[8] = {a.x, a.y, a.z, a.w, b.x, b.y, b.z, b.w};
#pragma unroll
  for (int j = 0; j < 8; ++j) {
    const uint16_t hb = f2bf(f[j]);
    const float fh = __uint_as_float((uint32_t)hb << 16);
    const uint16_t lb = f2bf(f[j] - fh);
    hi[j] = (short)hb;
    lo[j] = (short)lb;
  }
}

// ============================================================================
// Pre-kernel: split W (fp32, 1 MB) into bf16 hi/lo planes, fragment-linear.
// 64 blocks x 256 threads. Same f2bf split as the main kernel -> identical
// numerics to the validated in-kernel split.
// ============================================================================
__global__ __launch_bounds__(256)
void w_split_kernel(const float* __restrict__ W) {
  const int g = blockIdx.x * 256 + threadIdx.x;  // 0..16383
#pragma unroll
  for (int r = 0; r < 2; ++r) {
    const int u = g * 2 + r;        // unit id 0..32767 (one unit = 8 k of one e)
    const int e = u >> 9;           // 512 k-octets per expert
    const int k0 = (u & 511) * 8;
    const float* wp = W + (size_t)e * D_DIM + k0;
    const float4 a = *reinterpret_cast<const float4*>(wp);
    const float4 b = *reinterpret_cast<const float4*>(wp + 4);
    short8_t hi, lo;
    split8(a, b, hi, lo);
    const int ks = k0 >> 5, q = (k0 >> 3) & 3;
    const int subE = e >> 4, ee = e & 15;
    const int idx = ks * 2048 + subE * 512 + q * 128 + ee * 8;
    *reinterpret_cast<short8_t*>(Whi_g + idx) = hi;
    *reinterpret_cast<short8_t*>(Wlo_g + idx) = lo;
  }
}

// ============================================================================
// MFMA router kernel — BARRIER-FREE main loop. 512 blocks x 256 threads
// (4 waves). Block: 16 rows x 64 e; wave w owns the 16x16 tile at experts
// w*16..w*16+15 via mfma_f32_16x16x32_bf16 with the validated 3-product
// bf16-split (Alo*Bhi + Ahi*Blo + Ahi*Bhi, same order, same k order ->
// bitwise-identical logits to the staged version).
//
// A: each lane loads its fragment (8 consecutive floats of row lane&15 at
//    k-octet lane>>4) STRAIGHT from global h and splits in-register. Per
//    k-step the wave consumes exactly 16 fully-covered 128B-aligned lines,
//    shared by all 4 waves through L1. No LDS, no __syncthreads, no vmcnt(0)
//    drains — the compiler pipelines loads across the unrolled k-loop and
//    8 waves/CU provide the rest of the latency hiding.
// B: read from the fragment-linear global planes (L2/L3-resident, fully
//    coalesced 1KB per wave-instruction).
// ============================================================================
__global__ __launch_bounds__(256)
void router_mfma_kernel(const float* __restrict__ h,
                        const float* __restrict__ bias,
                        float* __restrict__ out,
                        unsigned char* __restrict__ flags) {
  __shared__ float logits_lds[ROWS * 65];  // 4.2 KB, +1 pad

  const int tid  = threadIdx.x;
  const int wave = tid >> 6;   // n_sub: experts wave*16..+15
  const int lane = tid & 63;
  const int row0 = blockIdx.x * ROWS;

  // A fragment address: m = lane&15, k-octet = lane>>4 (k = koct*8 + j)
  const int a_row  = lane & 15;
  const int a_koct = lane >> 4;
  const float* aptr = h + (size_t)(row0 + a_row) * D_DIM + a_koct * 8;

  // B fragment base: ee = lane&15, q = lane>>4
  const int b_off = wave * 512 + (lane >> 4) * 128 + (lane & 15) * 8;
  const short* bh_base = Whi_g + b_off;
  const short* bl_base = Wlo_g + b_off;

  f32x4 acc = {0.0f, 0.0f, 0.0f, 0.0f};

#pragma unroll 4
  for (int ks = 0; ks < NKSTEP; ++ks) {
    const float4 a0 = *reinterpret_cast<const float4*>(aptr + ks * 32);
    const float4 a1 = *reinterpret_cast<const float4*>(aptr + ks * 32 + 4);
    const short8_t bh = *reinterpret_cast<const short8_t*>(bh_base + (size_t)ks * 2048);
    const short8_t bl = *reinterpret_cast<const short8_t*>(bl_base + (size_t)ks * 2048);
    short8_t ah, al;
    split8(a0, a1, ah, al);
    acc = __builtin_amdgcn_mfma_f32_16x16x32_bf16(al, bh, acc, 0, 0, 0);
    acc = __builtin_amdgcn_mfma_f32_16x16x32_bf16(ah, bl, acc, 0, 0, 0);
    acc = __builtin_amdgcn_mfma_f32_16x16x32_bf16(ah, bh, acc, 0, 0, 0);
  }

  // epilogue: C/D layout col=lane&15, row=(lane>>4)*4+reg -> logits LDS
  {
    const int q   = lane >> 4;
    const int col = wave * 16 + (lane & 15);
#pragma unroll
    for (int reg = 0; reg < 4; ++reg) {
      const int m = q * 4 + reg;
      logits_lds[m * 65 + col] = acc[reg];
    }
  }
  __syncthreads();

  // finalize: wave handles rows 4*wave..+3, lane = expert — VALIDATED path
  const int e = lane;
  const double be = (double)bias[e];
  for (int rr = 0; rr < 4; ++rr) {
    const int rloc = wave * 4 + rr;
    const int t = row0 + rloc;
    const double logit = (double)logits_lds[rloc * 65 + e] + be;

    float mask, weight;
    double gap;
    finalize_row_f64(logit, e, t, mask, weight, gap);

    const int idx = t * 64 + e;
    out[idx]          = mask;
    out[TE + idx]     = weight;
    out[2 * TE + idx] = (float)logit;
    if (e == 0) flags[t] = (gap < GAP_MARGIN) ? 1 : 0;
  }
}

// ============================================================================
// Fixup kernel — VALIDATED per-row logic, 256 persistent blocks with a
// grid-stride scan over rows. The flag check is block-uniform so the
// __syncthreads inside the branch is safe; the trailing barrier protects
// red[][] reuse across flagged rows.
// ============================================================================
__global__ __launch_bounds__(256)
void router_fixup_kernel(const float* __restrict__ h,
                         const float* __restrict__ W,
                         const float* __restrict__ bias,
                         const unsigned char* __restrict__ flags,
                         float* __restrict__ out) {
  __shared__ double red[4][64];

  const int tid  = threadIdx.x;
  const int wv   = tid >> 6;
  const int lane = tid & 63;

  for (int t = blockIdx.x; t < T_DIM; t += 256) {
    if (flags[t] == 0) continue;

    const float* hrow = h + (size_t)t * D_DIM + wv * 1024;

    float hv[16];
#pragma unroll
    for (int j = 0; j < 16; ++j) hv[j] = hrow[j * 64 + lane];

    for (int e0 = 0; e0 < 64; e0 += 4) {
      const float* w0 = W + (size_t)(e0 + 0) * D_DIM + wv * 1024;
      const float* w1 = W + (size_t)(e0 + 1) * D_DIM + wv * 1024;
      const float* w2 = W + (size_t)(e0 + 2) * D_DIM + wv * 1024;
      const float* w3 = W + (size_t)(e0 + 3) * D_DIM + wv * 1024;
      double a0 = 0.0, a1 = 0.0, a2 = 0.0, a3 = 0.0;
#pragma unroll
      for (int j = 0; j < 16; ++j) {
        const double hd = (double)hv[j];
        a0 = fma((double)w0[j * 64 + lane], hd, a0);
        a1 = fma((double)w1[j * 64 + lane], hd, a1);
        a2 = fma((double)w2[j * 64 + lane], hd, a2);
        a3 = fma((double)w3[j * 64 + lane], hd, a3);
      }
#pragma unroll
      for (int off = 1; off < 64; off <<= 1) {
        a0 += __shfl_xor(a0, off, 64);
        a1 += __shfl_xor(a1, off, 64);
        a2 += __shfl_xor(a2, off, 64);
        a3 += __shfl_xor(a3, off, 64);
      }
      if (lane == e0 + 0) red[wv][lane] = a0;
      if (lane == e0 + 1) red[wv][lane] = a1;
      if (lane == e0 + 2) red[wv][lane] = a2;
      if (lane == e0 + 3) red[wv][lane] = a3;
    }
    __syncthreads();

    if (wv == 0) {
      const int e = lane;
      const double logit = ((red[0][e] + red[1][e]) + (red[2][e] + red[3][e]))
                           + (double)bias[e];
      float mask, weight;
      double gap;
      finalize_row_f64(logit, e, t, mask, weight, gap);

      const int idx = t * 64 + e;
      out[idx]          = mask;
      out[TE + idx]     = weight;
      out[2 * TE + idx] = (float)logit;
    }
    __syncthreads();  // protect red[][] before next flagged row
  }
}

extern "C" void kernel_launch(void* const* d_in, const int* in_sizes, int n_in,
                              void* d_out, int out_size, void* d_ws, size_t ws_size,
                              hipStream_t stream) {
  const float* h    = (const float*)d_in[0];
  const float* W    = (const float*)d_in[1];
  const float* bias = (const float*)d_in[2];
  // d_in[3] = k (always 8) — hard-coded top-8
  float* out = (float*)d_out;
  unsigned char* flags = (unsigned char*)d_ws;  // 8192 B, fully rewritten per call

  w_split_kernel<<<64, 256, 0, stream>>>(W);
  router_mfma_kernel<<<T_DIM / ROWS, 256, 0, stream>>>(h, bias, out, flags);
  router_fixup_kernel<<<256, 256, 0, stream>>>(h, W, bias, flags, out);
}

// Round 4
// 335.515 us; speedup vs baseline: 2.4265x; 2.4265x over previous
//
#include <hip/hip_runtime.h>
#include <stdint.h>
#include <math.h>

#define T_DIM 8192
#define D_DIM 4096
#define E_DIM 64
#define TE (T_DIM * E_DIM)  // 524288
#define GAP_MARGIN 2e-3     // > 2x provable worst-case bf16-split logit error (9.4e-4)
#define ROWS 16             // rows per block (mfma kernel)
#define NKSTEP (D_DIM / 32) // 128 MFMA k-steps
#define FIX_WAVES 8
#define FIX_COLS (D_DIM / FIX_WAVES)  // 512 cols per wave

typedef __attribute__((ext_vector_type(8))) short short8_t;  // 8 bf16 (4 VGPRs)
typedef __attribute__((ext_vector_type(4))) float f32x4;

// ============================================================================
// W bf16 hi/lo planes in fragment-linear order, filled once per call by
// w_split_kernel. idx = ks*2048 + subE*512 + q*128 + ee*8 + j where
// e = subE*16+ee, k = ks*32 + q*8 + j. The per-wave B-fragment read
// (n=lane&15 -> ee, q=lane>>4) is a fully-coalesced 1KB global_load_dwordx4
// per wave at address plane + ks*2048 + b_off — B never touches LDS.
// ============================================================================
__device__ __align__(16) short Whi_g[E_DIM * D_DIM];  // 512 KB
__device__ __align__(16) short Wlo_g[E_DIM * D_DIM];  // 512 KB

// ============================================================================
// Threefry-2x32, key = (0, 42), 20 rounds — VALIDATED (prior session r3/4/5)
// ============================================================================
__device__ __forceinline__ void threefry2x32_k42(uint32_t x0, uint32_t x1,
                                                 uint32_t& o0, uint32_t& o1) {
  const uint32_t ks0 = 0u, ks1 = 42u;
  const uint32_t ks2 = 0x1BD11BDAu ^ ks0 ^ ks1;
  x0 += ks0; x1 += ks1;
#define TF_RND(r) { x0 += x1; x1 = (x1 << (r)) | (x1 >> (32 - (r))); x1 ^= x0; }
  TF_RND(13) TF_RND(15) TF_RND(26) TF_RND(6)   x0 += ks1; x1 += ks2 + 1u;
  TF_RND(17) TF_RND(29) TF_RND(16) TF_RND(24)  x0 += ks2; x1 += ks0 + 2u;
  TF_RND(13) TF_RND(15) TF_RND(26) TF_RND(6)   x0 += ks0; x1 += ks1 + 3u;
  TF_RND(17) TF_RND(29) TF_RND(16) TF_RND(24)  x0 += ks1; x1 += ks2 + 4u;
  TF_RND(13) TF_RND(15) TF_RND(26) TF_RND(6)   x0 += ks2; x1 += ks0 + 5u;
#undef TF_RND
  o0 = x0; o1 = x1;
}

__device__ __forceinline__ uint32_t jax_random_bits32(uint32_t j) {
  uint32_t o0, o1;
  threefry2x32_k42(0u, j, o0, o1);
  return o0 ^ o1;
}

// f64 finalize per row (lane = expert) — VALIDATED, unchanged
__device__ __forceinline__ void finalize_row_f64(double logit, int e, int t,
                                                 float& mask_out, float& weight_out,
                                                 double& gap_out) {
  double m = logit;
#pragma unroll
  for (int off = 1; off < 64; off <<= 1) {
    const double om = __shfl_xor(m, off, 64);
    m = (om > m) ? om : m;
  }
  const double pe = exp(logit - m);
  double s = pe;
#pragma unroll
  for (int off = 1; off < 64; off <<= 1) s += __shfl_xor(s, off, 64);
  weight_out = (float)(pe / s);

  const int idx = t * 64 + e;
  const uint32_t bits = jax_random_bits32((uint32_t)idx);
  const float f01 = __uint_as_float((bits >> 9) | 0x3f800000u) - 1.0f;
  const float minv = 1e-6f;
  const float maxv = 0.999999f;
  float u = __fadd_rn(__fmul_rn(f01, maxv - minv), minv);
  u = fmaxf(minv, u);
  const double g = -log(-log((double)u));
  const double sel = logit + g;

  float mask = 0.0f;
  double cur = sel;
  double v8 = 0.0, v9 = 0.0;
  for (int it = 0; it < 9; ++it) {
    double v = cur;
    int vi = e;
#pragma unroll
    for (int off = 1; off < 64; off <<= 1) {
      const double ov = __shfl_xor(v, off, 64);
      const int    oi = __shfl_xor(vi, off, 64);
      if (ov > v || (ov == v && oi < vi)) { v = ov; vi = oi; }
    }
    if (it < 8) {
      if (vi == e) { mask = 1.0f; cur = -__builtin_inf(); }
      if (it == 7) v8 = v;
    } else {
      v9 = v;
    }
  }
  mask_out = mask;
  gap_out = v8 - v9;
}

// fp32 -> bf16 (RNE, finite inputs only)
__device__ __forceinline__ uint16_t f2bf(float f) {
  const uint32_t x = __float_as_uint(f);
  return (uint16_t)((x + 0x7FFFu + ((x >> 16) & 1u)) >> 16);
}

// split 8 consecutive floats into bf16 hi/lo short8 fragments
__device__ __forceinline__ void split8(const float4 a, const float4 b,
                                       short8_t& hi, short8_t& lo) {
  const float f[8] = {a.x, a.y, a.z, a.w, b.x, b.y, b.z, b.w};
#pragma unroll
  for (int j = 0; j < 8; ++j) {
    const uint16_t hb = f2bf(f[j]);
    const float fh = __uint_as_float((uint32_t)hb << 16);
    const uint16_t lb = f2bf(f[j] - fh);
    hi[j] = (short)hb;
    lo[j] = (short)lb;
  }
}

// ============================================================================
// Pre-kernel: split W (fp32, 1 MB) into bf16 hi/lo planes, fragment-linear.
// Same f2bf split as the main kernel -> identical numerics.
// ============================================================================
__global__ __launch_bounds__(256)
void w_split_kernel(const float* __restrict__ W) {
  const int g = blockIdx.x * 256 + threadIdx.x;  // 0..16383
#pragma unroll
  for (int r = 0; r < 2; ++r) {
    const int u = g * 2 + r;        // unit id 0..32767 (one unit = 8 k of one e)
    const int e = u >> 9;           // 512 k-octets per expert
    const int k0 = (u & 511) * 8;
    const float* wp = W + (size_t)e * D_DIM + k0;
    const float4 a = *reinterpret_cast<const float4*>(wp);
    const float4 b = *reinterpret_cast<const float4*>(wp + 4);
    short8_t hi, lo;
    split8(a, b, hi, lo);
    const int ks = k0 >> 5, q = (k0 >> 3) & 3;
    const int subE = e >> 4, ee = e & 15;
    const int idx = ks * 2048 + subE * 512 + q * 128 + ee * 8;
    *reinterpret_cast<short8_t*>(Whi_g + idx) = hi;
    *reinterpret_cast<short8_t*>(Wlo_g + idx) = lo;
  }
}

// ============================================================================
// MFMA router kernel — BARRIER-FREE main loop (unchanged from round 3; its
// solo duration gets measured this round). 512 blocks x 256 threads (4 waves).
// Block: 16 rows x 64 e; wave w owns the 16x16 tile at experts w*16..+15 via
// mfma_f32_16x16x32_bf16 with the validated 3-product bf16-split.
// ============================================================================
__global__ __launch_bounds__(256)
void router_mfma_kernel(const float* __restrict__ h,
                        const float* __restrict__ bias,
                        float* __restrict__ out,
                        unsigned char* __restrict__ flags) {
  __shared__ float logits_lds[ROWS * 65];  // 4.2 KB, +1 pad

  const int tid  = threadIdx.x;
  const int wave = tid >> 6;   // n_sub: experts wave*16..+15
  const int lane = tid & 63;
  const int row0 = blockIdx.x * ROWS;

  // A fragment address: m = lane&15, k-octet = lane>>4 (k = koct*8 + j)
  const int a_row  = lane & 15;
  const int a_koct = lane >> 4;
  const float* aptr = h + (size_t)(row0 + a_row) * D_DIM + a_koct * 8;

  // B fragment base: ee = lane&15, q = lane>>4
  const int b_off = wave * 512 + (lane >> 4) * 128 + (lane & 15) * 8;
  const short* bh_base = Whi_g + b_off;
  const short* bl_base = Wlo_g + b_off;

  f32x4 acc = {0.0f, 0.0f, 0.0f, 0.0f};

#pragma unroll 4
  for (int ks = 0; ks < NKSTEP; ++ks) {
    const float4 a0 = *reinterpret_cast<const float4*>(aptr + ks * 32);
    const float4 a1 = *reinterpret_cast<const float4*>(aptr + ks * 32 + 4);
    const short8_t bh = *reinterpret_cast<const short8_t*>(bh_base + (size_t)ks * 2048);
    const short8_t bl = *reinterpret_cast<const short8_t*>(bl_base + (size_t)ks * 2048);
    short8_t ah, al;
    split8(a0, a1, ah, al);
    acc = __builtin_amdgcn_mfma_f32_16x16x32_bf16(al, bh, acc, 0, 0, 0);
    acc = __builtin_amdgcn_mfma_f32_16x16x32_bf16(ah, bl, acc, 0, 0, 0);
    acc = __builtin_amdgcn_mfma_f32_16x16x32_bf16(ah, bh, acc, 0, 0, 0);
  }

  // epilogue: C/D layout col=lane&15, row=(lane>>4)*4+reg -> logits LDS
  {
    const int q   = lane >> 4;
    const int col = wave * 16 + (lane & 15);
#pragma unroll
    for (int reg = 0; reg < 4; ++reg) {
      const int m = q * 4 + reg;
      logits_lds[m * 65 + col] = acc[reg];
    }
  }
  __syncthreads();

  // finalize: wave handles rows 4*wave..+3, lane = expert — VALIDATED path
  const int e = lane;
  const double be = (double)bias[e];
  for (int rr = 0; rr < 4; ++rr) {
    const int rloc = wave * 4 + rr;
    const int t = row0 + rloc;
    const double logit = (double)logits_lds[rloc * 65 + e] + be;

    float mask, weight;
    double gap;
    finalize_row_f64(logit, e, t, mask, weight, gap);

    const int idx = t * 64 + e;
    out[idx]          = mask;
    out[TE + idx]     = weight;
    out[2 * TE + idx] = (float)logit;
    if (e == 0) flags[t] = (gap < GAP_MARGIN) ? 1 : 0;
  }
}

// ============================================================================
// Fixup kernel — REDESIGNED for parallel W traffic. One block (512 thr,
// 8 waves) per row, early exit when unflagged. lane = expert: each lane
// streams W[e][slice] as dense contiguous float4 loads (full line use, 4
// interleaved f64 chains — no serial expert-groups, no f64 wave shuffles).
// h row staged in LDS, read as uniform-address broadcasts (conflict-free).
// Per flagged row: ~1 MB of W at full pipeline depth ≈ 8 µs (was ~100 µs).
// Finalize path (wave 0) is the VALIDATED f64 routine, bias added at the end
// as before; all dot sums pure f64 (order change ~1e-15 rel — no decision
// scale is anywhere near that).
// ============================================================================
__global__ __launch_bounds__(512)
void router_fixup_kernel(const float* __restrict__ h,
                         const float* __restrict__ W,
                         const float* __restrict__ bias,
                         const unsigned char* __restrict__ flags,
                         float* __restrict__ out) {
  const int t = blockIdx.x;
  if (flags[t] == 0) return;

  __shared__ float  h_lds[D_DIM];          // 16 KB
  __shared__ double red[FIX_WAVES][64];    // 4 KB

  const int tid  = threadIdx.x;
  const int wv   = tid >> 6;
  const int lane = tid & 63;

  // stage h row, coalesced float4 (512 thr x 2 x 16B = 16 KB)
  {
    const float4* hrow4 = reinterpret_cast<const float4*>(h + (size_t)t * D_DIM);
    float4* hl4 = reinterpret_cast<float4*>(h_lds);
    hl4[tid]       = hrow4[tid];
    hl4[tid + 512] = hrow4[tid + 512];
  }
  __syncthreads();

  // lane = expert e; wave wv covers cols [wv*512, wv*512+512)
  const int e = lane;
  const float* wrow = W + (size_t)e * D_DIM + wv * FIX_COLS;
  const float* hseg = h_lds + wv * FIX_COLS;

  double acc0 = 0.0, acc1 = 0.0, acc2 = 0.0, acc3 = 0.0;
#pragma unroll 8
  for (int c = 0; c < FIX_COLS; c += 16) {
    const float4 w0 = *reinterpret_cast<const float4*>(wrow + c);
    const float4 w1 = *reinterpret_cast<const float4*>(wrow + c + 4);
    const float4 w2 = *reinterpret_cast<const float4*>(wrow + c + 8);
    const float4 w3 = *reinterpret_cast<const float4*>(wrow + c + 12);
    acc0 = fma((double)w0.x, (double)hseg[c + 0], acc0);
    acc0 = fma((double)w0.y, (double)hseg[c + 1], acc0);
    acc0 = fma((double)w0.z, (double)hseg[c + 2], acc0);
    acc0 = fma((double)w0.w, (double)hseg[c + 3], acc0);
    acc1 = fma((double)w1.x, (double)hseg[c + 4], acc1);
    acc1 = fma((double)w1.y, (double)hseg[c + 5], acc1);
    acc1 = fma((double)w1.z, (double)hseg[c + 6], acc1);
    acc1 = fma((double)w1.w, (double)hseg[c + 7], acc1);
    acc2 = fma((double)w2.x, (double)hseg[c + 8], acc2);
    acc2 = fma((double)w2.y, (double)hseg[c + 9], acc2);
    acc2 = fma((double)w2.z, (double)hseg[c + 10], acc2);
    acc2 = fma((double)w2.w, (double)hseg[c + 11], acc2);
    acc3 = fma((double)w3.x, (double)hseg[c + 12], acc3);
    acc3 = fma((double)w3.y, (double)hseg[c + 13], acc3);
    acc3 = fma((double)w3.z, (double)hseg[c + 14], acc3);
    acc3 = fma((double)w3.w, (double)hseg[c + 15], acc3);
  }
  red[wv][e] = (acc0 + acc1) + (acc2 + acc3);
  __syncthreads();

  if (wv == 0) {
    double s = red[0][e];
#pragma unroll
    for (int i = 1; i < FIX_WAVES; ++i) s += red[i][e];
    const double logit = s + (double)bias[e];

    float mask, weight;
    double gap;
    finalize_row_f64(logit, e, t, mask, weight, gap);

    const int idx = t * 64 + e;
    out[idx]          = mask;
    out[TE + idx]     = weight;
    out[2 * TE + idx] = (float)logit;
  }
}

extern "C" void kernel_launch(void* const* d_in, const int* in_sizes, int n_in,
                              void* d_out, int out_size, void* d_ws, size_t ws_size,
                              hipStream_t stream) {
  const float* h    = (const float*)d_in[0];
  const float* W    = (const float*)d_in[1];
  const float* bias = (const float*)d_in[2];
  // d_in[3] = k (always 8) — hard-coded top-8
  float* out = (float*)d_out;
  unsigned char* flags = (unsigned char*)d_ws;  // 8192 B, fully rewritten per call

  w_split_kernel<<<64, 256, 0, stream>>>(W);
  router_mfma_kernel<<<T_DIM / ROWS, 256, 0, stream>>>(h, bias, out, flags);
  router_fixup_kernel<<<T_DIM, 512, 0, stream>>>(h, W, bias, flags, out);
}